// Round 11
// baseline (140.178 us; speedup 1.0000x reference)
//
#include <hip/hip_runtime.h>

// LIF neuron bank: B=16, N=2048, T=1000.
//
// R11: block-level TLP. Every prior structure ran 512 blocks = 2 blocks/CU;
// all restructures (store shape R4/R6/R7, barrier drain R3, loader MLP R10)
// were null or losses because each CU hosted only 2 lock-stepped phase
// pipelines -- the fixed per-phase latency (~6.9us) was exposed, not hidden.
// fillBuffer / lif_expand stream at 6-7 TB/s with MANY independent blocks.
// Fix: 16 neurons/block -> 2048 blocks = 8 blocks/CU (24 waves/CU), LDS
// 20KB/block. 8 staggered pipelines/CU hide each other's phase latency.
//
// K1 (2048 blocks x 192): 16 phases of 64 steps, one LDS barrier/phase.
//   w0 compute (lanes 0-15): u from LDS ring (swizzled ds_read_b128, staged
//      2 groups ahead), serial chain, v -> LDS dbuf, spike bits -> d_ws.
//   w1 loader: global_load_lds dwordx4, 4 insts/chunk (rows 4j..4j+3 x 256B,
//      global source pre-swizzled, LDS dest linear); 3-ring, 2 chunks ahead,
//      counted s_waitcnt vmcnt(4); never blocks on stores (has none).
//   w2 v-storer: 256B-per-row segments (R4-proven), one phase behind.
// K2 (4096 blocks x 256): bits -> exact 1.0f/0.0f spikes, pure streaming.
//
// FP discipline: reference does NOT contract mul+add into FMA; use
// __fmul_rn/__fadd_rn/__fsub_rn to stay bit-exact (R0-R10: absmax 0.0).

constexpr int B_ = 16;
constexpr int N_ = 2048;
constexpr int T_ = 1000;
constexpr int RPB = 16;                // rows (neurons) per block
constexpr int CH = 64;                 // steps per chunk
constexpr int NF4 = CH / 4;            // 16 float4 per row per chunk
constexpr int NCH = 16;                // chunks; last has 40 valid steps
constexpr long NEUR = (long)B_ * N_;   // 32768

#define LGKM0()                                                \
    do {                                                       \
        asm volatile("s_waitcnt lgkmcnt(0)" ::: "memory");     \
        __builtin_amdgcn_sched_barrier(0);                     \
    } while (0)

__device__ __forceinline__ void gload_lds16(const float* g, void* lds) {
    __builtin_amdgcn_global_load_lds(
        (const __attribute__((address_space(1))) void*)g,
        (__attribute__((address_space(3))) void*)lds, 16, 0, 0);
}

__global__ __launch_bounds__(192, 6) void lif_pass1(
    const float* __restrict__ u,           // (B, N, T)
    const float* __restrict__ theta_base,  // N floats
    float* __restrict__ vhist,             // (B, N, T)
    unsigned long long* __restrict__ wsbits) // [chunk][neuron] spike bits
{
    __shared__ float4 u_ring[3][RPB][NF4];   // 12 KiB
    __shared__ float4 v_lds[2][RPB][NF4];    //  8 KiB

    const int lane = threadIdx.x & 63;
    const int wid = threadIdx.x >> 6;
    const int blk0 = blockIdx.x * RPB;

    if (wid == 1) {
        // ---------------- loader wave ----------------
        const float* ub = u + (size_t)blk0 * T_;
        const int rs = lane >> 4;      // row-sub within 4-row group
        const int sl = lane & 15;      // phys slot this lane fills

        auto issue = [&](int c) {
            const int bq = c % 3;
            if (c < 15) {
                const int t0 = c * CH;
#pragma unroll
                for (int j = 0; j < 4; ++j) {
                    const int r = 4 * j + rs;
                    // pre-swizzled global source; LDS dest linear (1KB/inst)
                    const float* g =
                        ub + (size_t)r * T_ + t0 + 4 * (sl ^ (r & 15));
                    gload_lds16(g, &u_ring[bq][4 * j][0]);
                }
            } else {
                // tail chunk: logical tf = sl ^ (r&15); only tf<10 valid
#pragma unroll
                for (int j = 0; j < 4; ++j) {
                    const int r = 4 * j + rs;
                    const int tf = sl ^ (r & 15);
                    if (tf < 10) {
                        const float* g = ub + (size_t)r * T_ + 960 + 4 * tf;
                        gload_lds16(g, &u_ring[bq][4 * j][0]);
                    }
                }
            }
        };

        issue(0);
        issue(1);
        asm volatile("s_waitcnt vmcnt(4)" ::: "memory");   // chunk 0 landed
        __builtin_amdgcn_sched_barrier(0);
        __builtin_amdgcn_s_barrier();                      // B(-1)
#pragma unroll 1
        for (int c = 0; c < NCH; ++c) {
            if (c + 2 < NCH) {
                issue(c + 2);          // into ring buf just freed
                asm volatile("s_waitcnt vmcnt(4)" ::: "memory"); // c+1 landed
            } else {
                asm volatile("s_waitcnt vmcnt(0)" ::: "memory");
            }
            __builtin_amdgcn_sched_barrier(0);
            __builtin_amdgcn_s_barrier();
            __builtin_amdgcn_sched_barrier(0);
        }
    } else if (wid == 0) {
        // ---------------- compute wave (lanes 0..15) ----------------
        const float tb = theta_base[(blk0 + (lane & 15)) & (N_ - 1)];
        const float c5 = __fmul_rn(tb, 0.005f);   // tb * (1-0.995) rounded
        float v = 0.0f, theta = tb, ref = 0.0f;

        __builtin_amdgcn_s_barrier();              // B(-1)
#pragma unroll 1
        for (int c = 0; c < NCH; ++c) {
            const int bq = c % 3;
            const int pb = c & 1;
            if (lane < RPB) {
                unsigned blo = 0, bhi = 0;
                // staged groups of 4 float4 (16 steps): read g+1 while
                // chaining g -> ~32 live VGPRs for u instead of 64.
                float4 ga[4], gb[4];
#pragma unroll
                for (int i = 0; i < 4; ++i)
                    ga[i] = u_ring[bq][lane][(0 + i) ^ lane];

                auto chain16 = [&](const float4 (&gr)[4], int gbase,
                                   unsigned& bw) {
#pragma unroll
                    for (int i = 0; i < 4; ++i) {
                        const int tf = gbase + i;
                        const float uin[4] = {gr[i].x, gr[i].y,
                                              gr[i].z, gr[i].w};
                        float vo[4];
#pragma unroll
                        for (int k = 0; k < 4; ++k) {
                            // u_eff = u_t * (1 - (ref>0))
                            const float ueff = (ref > 0.0f) ? 0.0f : uin[k];
                            // v = 0.95*v + u_eff  (separate mul/add, no FMA)
                            v = __fadd_rn(__fmul_rn(0.95f, v), ueff);
                            // s = (v - theta >= 0)
                            const float d = __fsub_rn(v, theta);
                            const bool s = (d >= 0.0f);
                            // v -= s*theta
                            v = s ? __fsub_rn(v, theta) : v;
                            // ref = max(ref-1,0); if (s) ref = 2
                            ref = fmaxf(__fsub_rn(ref, 1.0f), 0.0f);
                            ref = s ? 2.0f : ref;
                            // theta = theta*0.995 + tb*0.005 + 0.35*s
                            theta = __fadd_rn(__fmul_rn(theta, 0.995f), c5);
                            theta = s ? __fadd_rn(theta, 0.35f) : theta;

                            bw |= (s ? 1u : 0u) << (4 * ((tf & 7)) + k);
                            vo[k] = v;
                        }
                        v_lds[pb][lane][tf ^ lane] =
                            make_float4(vo[0], vo[1], vo[2], vo[3]);
                    }
                };

#pragma unroll
                for (int i = 0; i < 4; ++i)
                    gb[i] = u_ring[bq][lane][(4 + i) ^ lane];
                chain16(ga, 0, blo);
#pragma unroll
                for (int i = 0; i < 4; ++i)
                    ga[i] = u_ring[bq][lane][(8 + i) ^ lane];
                chain16(gb, 4, blo);
#pragma unroll
                for (int i = 0; i < 4; ++i)
                    gb[i] = u_ring[bq][lane][(12 + i) ^ lane];
                chain16(ga, 8, bhi);
                chain16(gb, 12, bhi);

                // spike bits -> workspace (128B contiguous per block-phase)
                wsbits[(size_t)c * NEUR + blk0 + lane] =
                    ((unsigned long long)bhi << 32) | blo;
            }
            LGKM0();
            __builtin_amdgcn_s_barrier();
        }
    } else {
        // ---------------- v-storer wave ----------------
        float* gv = vhist + (size_t)blk0 * T_;
        const int rs = lane >> 4;
        const int sl = lane & 15;

        __builtin_amdgcn_s_barrier();              // B(-1)
#pragma unroll 1
        for (int c = 0; c < NCH; ++c) {
            if (c >= 1) {
                const int pc = c - 1;
                const int pb = pc & 1;
                const int t0 = pc * CH;
#pragma unroll
                for (int j = 0; j < 4; ++j) {
                    const int r = 4 * j + rs;
                    const float4 w = v_lds[pb][r][sl ^ (r & 15)];
                    *(float4*)(gv + (size_t)r * T_ + t0 + 4 * sl) = w;
                }
            }
            LGKM0();
            __builtin_amdgcn_s_barrier();
        }
        // epilogue: tail chunk (c=15, pb=1): 10 valid float4 per row
#pragma unroll
        for (int j = 0; j < 4; ++j) {
            const int r = 4 * j + rs;
            if (sl < 10) {
                const float4 w = v_lds[1][r][sl ^ (r & 15)];
                *(float4*)(gv + (size_t)r * T_ + 960 + 4 * sl) = w;
            }
        }
    }
}

__global__ __launch_bounds__(256) void lif_expand(
    const unsigned* __restrict__ wsbits,  // u32 view: [chunk][neuron][2]
    float* __restrict__ spikes)           // (B, N, T)
{
    const int tid = blockIdx.x * 256 + threadIdx.x;
    const int lane = tid & 63;
    const long wavei = tid >> 6;              // 0..16383
    const long row = 2 * wavei + (lane >> 5); // 2 adjacent rows per wave
    const int k = lane & 31;                  // 2*chunk + half
    const int c = k >> 1;
    const int half = k & 1;

    const unsigned w = wsbits[(((size_t)c * NEUR + row) << 1) | half];
    const int t0 = 64 * c + 32 * half;
    float* gp = spikes + (size_t)row * T_ + t0;

#pragma unroll
    for (int j = 0; j < 8; ++j) {
        if (t0 + 4 * j < T_) {                // only the last half trims
            float4 f;
            f.x = ((w >> (4 * j + 0)) & 1u) ? 1.0f : 0.0f;
            f.y = ((w >> (4 * j + 1)) & 1u) ? 1.0f : 0.0f;
            f.z = ((w >> (4 * j + 2)) & 1u) ? 1.0f : 0.0f;
            f.w = ((w >> (4 * j + 3)) & 1u) ? 1.0f : 0.0f;
            *(float4*)(gp + 4 * j) = f;
        }
    }
}

extern "C" void kernel_launch(void* const* d_in, const int* in_sizes, int n_in,
                              void* d_out, int out_size, void* d_ws, size_t ws_size,
                              hipStream_t stream) {
    const float* u = (const float*)d_in[0];           // (B,N,T)
    const float* theta_base = (const float*)d_in[1];  // (1,N,1)
    float* out = (float*)d_out;
    float* spikes = out;                               // first output
    float* vhist = out + (size_t)B_ * N_ * T_;         // second output
    unsigned long long* wsbits = (unsigned long long*)d_ws;  // 4 MiB used

    lif_pass1<<<(int)(NEUR / RPB), 192, 0, stream>>>(u, theta_base, vhist,
                                                     wsbits);
    // one wave per 2 rows: NEUR/2 waves -> NEUR/8 blocks of 256 threads
    lif_expand<<<(int)(NEUR / 8), 256, 0, stream>>>((const unsigned*)wsbits,
                                                    spikes);
}

// Round 13
// 128.502 us; speedup vs baseline: 1.0909x; 1.0909x over previous
//
#include <hip/hip_runtime.h>

// LIF neuron bank: B=16, N=2048, T=1000.
//
// R13: barrier-free fused wave. Evidence: stores complete into L2 (R3 drain
// null), traffic is near-ideal, compute ~10us total -- yet every phase-
// structured design (R2-R11, 2-3 waves rendezvousing 16-32x) pins at
// ~6.5us/phase with only 2 blocks/CU to hide exposed latency. R13 removes
// the rendezvous entirely: one self-sufficient wave per 64 neurons,
// free-running 16 chunks of 64 steps:
//   - u register-prefetched TWO chunks deep (3 named bufs A/Bb/C, ~220 VGPR);
//   - serial LIF chain; v float4 -> wave-private LDS (XOR swizzle, dbuf),
//     wave-synchronous transpose (DS pipe is in-order per wave + lgkmcnt(0));
//   - 16 v-store insts/chunk: rows 4k..4k+3 x 256B contiguous (R4-proven);
//   - spikes -> 64-bit masks to d_ws (512B/wave/chunk, off the serial chain).
// vmcnt queue: ~33 ops/chunk; consuming a buf loaded 2 chunks ago waits only
// on the oldest loads (counted vmcnt), never drains younger stores.
// Pass2 (proven R10): bits -> exact 1.0f/0.0f, 4096 blocks, ~6 TB/s.
//
// FP discipline: reference does NOT contract mul+add into FMA; use
// __fmul_rn/__fadd_rn/__fsub_rn to stay bit-exact (R0-R11: absmax 0.0).

constexpr int B_ = 16;
constexpr int N_ = 2048;
constexpr int T_ = 1000;
constexpr int CH = 64;                 // steps per chunk
constexpr long NEUR = (long)B_ * N_;   // 32768

__global__ __launch_bounds__(64) void lif_pass1(
    const float* __restrict__ u,            // (B, N, T)
    const float* __restrict__ theta_base,   // N floats
    float* __restrict__ vhist,              // (B, N, T)
    unsigned long long* __restrict__ wsbits) // [chunk][neuron] spike bits
{
    __shared__ float4 vt[2][64][16];        // 32 KiB, wave-private dbuf

    const int lane = threadIdx.x;           // blockDim = 64
    const int blk0 = blockIdx.x * 64;
    const float tb = theta_base[(blk0 + lane) & (N_ - 1)];
    const float c5 = __fmul_rn(tb, 0.005f); // tb * (1-0.995) rounded
    float v = 0.0f, theta = tb, ref = 0.0f;
    const float* up = u + (size_t)(blk0 + lane) * T_;
    float* gv = vhist + (size_t)blk0 * T_;
    const int sw = lane & 15;
    const int rs = lane >> 4;

    float4 A[16], Bb[16], C[16];            // named bufs: static indexing

    auto loadf = [&](float4 (&b)[16], int c) {
#pragma unroll
        for (int i = 0; i < 16; ++i)
            b[i] = *(const float4*)(up + CH * c + 4 * i);
    };
    auto loadt = [&](float4 (&b)[16]) {     // tail: t 960..999 = 10 f4
#pragma unroll
        for (int i = 0; i < 10; ++i)
            b[i] = *(const float4*)(up + 960 + 4 * i);
    };

    auto step4 = [&](const float4 u4, unsigned& bw, int sh) -> float4 {
        const float uin[4] = {u4.x, u4.y, u4.z, u4.w};
        float vo[4];
#pragma unroll
        for (int k = 0; k < 4; ++k) {
            // u_eff = u_t * (1 - (ref>0))
            const float ueff = (ref > 0.0f) ? 0.0f : uin[k];
            // v = 0.95*v + u_eff   (separate mul/add, no FMA)
            v = __fadd_rn(__fmul_rn(0.95f, v), ueff);
            // s = (v - theta >= 0)
            const float d = __fsub_rn(v, theta);
            const bool s = (d >= 0.0f);
            // v -= s*theta
            v = s ? __fsub_rn(v, theta) : v;
            // ref = max(ref-1,0); if (s) ref = 2
            ref = fmaxf(__fsub_rn(ref, 1.0f), 0.0f);
            ref = s ? 2.0f : ref;
            // theta = theta*0.995 + tb*0.005 + 0.35*s
            theta = __fadd_rn(__fmul_rn(theta, 0.995f), c5);
            theta = s ? __fadd_rn(theta, 0.35f) : theta;

            bw |= (s ? 1u : 0u) << (sh + k);   // off the serial chain
            vo[k] = v;
        }
        return make_float4(vo[0], vo[1], vo[2], vo[3]);
    };

    auto do_chunk = [&](const float4 (&b)[16], int c) {
        const int pb = c & 1;
        unsigned blo = 0, bhi = 0;
#pragma unroll
        for (int f = 0; f < 16; ++f) {
            float4 v4 = (f < 8) ? step4(b[f], blo, 4 * f)
                                : step4(b[f], bhi, 4 * (f - 8));
            vt[pb][lane][f ^ sw] = v4;
        }
        wsbits[(size_t)c * NEUR + blk0 + lane] =
            ((unsigned long long)bhi << 32) | blo;
        asm volatile("s_waitcnt lgkmcnt(0)" ::: "memory");
        const int t0 = CH * c;
        // wave-synchronous transpose read + 256B-contiguous row stores
#pragma unroll
        for (int k = 0; k < 16; ++k) {
            const int r = 4 * k + rs;
            const float4 w = vt[pb][r][sw ^ (r & 15)];
            *(float4*)(gv + (size_t)r * T_ + t0 + 4 * sw) = w;
        }
    };

    auto do_tail = [&](const float4 (&b)[16]) {   // c = 15: 40 valid steps
        const int pb = 1;
        unsigned blo = 0, bhi = 0;
#pragma unroll
        for (int f = 0; f < 10; ++f) {
            float4 v4 = (f < 8) ? step4(b[f], blo, 4 * f)
                                : step4(b[f], bhi, 4 * (f - 8));
            vt[pb][lane][f ^ sw] = v4;
        }
        wsbits[(size_t)15 * NEUR + blk0 + lane] =
            ((unsigned long long)bhi << 32) | blo;
        asm volatile("s_waitcnt lgkmcnt(0)" ::: "memory");
#pragma unroll
        for (int k = 0; k < 16; ++k) {
            const int r = 4 * k + rs;
            if (sw < 10) {
                const float4 w = vt[pb][r][sw ^ (r & 15)];
                *(float4*)(gv + (size_t)r * T_ + 960 + 4 * sw) = w;
            }
        }
    };

    // depth-2 software pipeline over 15 full chunks (5 triples) + tail
    loadf(A, 0);
    loadf(Bb, 1);
#pragma unroll 1
    for (int g = 0; g < 5; ++g) {
        loadf(C, 3 * g + 2);
        do_chunk(A, 3 * g);
        if (3 * g + 3 < 15) loadf(A, 3 * g + 3);
        else                loadt(A);           // g==4: tail into A
        do_chunk(Bb, 3 * g + 1);
        if (3 * g + 4 < 15) loadf(Bb, 3 * g + 4);
        do_chunk(C, 3 * g + 2);
    }
    do_tail(A);
}

__global__ __launch_bounds__(256) void lif_expand(
    const unsigned* __restrict__ wsbits,  // u32 view: [chunk][neuron][2]
    float* __restrict__ spikes)           // (B, N, T)
{
    const int tid = blockIdx.x * 256 + threadIdx.x;
    const int lane = tid & 63;
    const long wavei = tid >> 6;              // 0..16383
    const long row = 2 * wavei + (lane >> 5); // 2 adjacent rows per wave
    const int k = lane & 31;                  // 2*chunk + half
    const int c = k >> 1;
    const int half = k & 1;

    const unsigned w = wsbits[(((size_t)c * NEUR + row) << 1) | half];
    const int t0 = 64 * c + 32 * half;
    float* gp = spikes + (size_t)row * T_ + t0;

#pragma unroll
    for (int j = 0; j < 8; ++j) {
        if (t0 + 4 * j < T_) {                // only the last half trims
            float4 f;
            f.x = ((w >> (4 * j + 0)) & 1u) ? 1.0f : 0.0f;
            f.y = ((w >> (4 * j + 1)) & 1u) ? 1.0f : 0.0f;
            f.z = ((w >> (4 * j + 2)) & 1u) ? 1.0f : 0.0f;
            f.w = ((w >> (4 * j + 3)) & 1u) ? 1.0f : 0.0f;
            *(float4*)(gp + 4 * j) = f;
        }
    }
}

extern "C" void kernel_launch(void* const* d_in, const int* in_sizes, int n_in,
                              void* d_out, int out_size, void* d_ws, size_t ws_size,
                              hipStream_t stream) {
    const float* u = (const float*)d_in[0];           // (B,N,T)
    const float* theta_base = (const float*)d_in[1];  // (1,N,1)
    float* out = (float*)d_out;
    float* spikes = out;                               // first output
    float* vhist = out + (size_t)NEUR * T_;            // second output
    unsigned long long* wsbits = (unsigned long long*)d_ws;  // 4 MiB used

    lif_pass1<<<(int)(NEUR / 64), 64, 0, stream>>>(u, theta_base, vhist,
                                                   wsbits);
    // one wave per 2 rows: NEUR/2 waves -> NEUR/8 blocks of 256 threads
    lif_expand<<<(int)(NEUR / 8), 256, 0, stream>>>((const unsigned*)wsbits,
                                                    spikes);
}